// Round 1
// baseline (11592.078 us; speedup 1.0000x reference)
//
#include <hip/hip_runtime.h>
#include <math.h>

#define KV 2048
#define KE 512
#define KH 1024
#define KB 128
#define KL 256
#define KH3 3072
#define TCH 32

typedef __attribute__((ext_vector_type(8))) short s8v;     // 8 bf16 (4 VGPRs)
typedef __attribute__((ext_vector_type(8))) unsigned short u16x8;
typedef __attribute__((ext_vector_type(4))) float f4v;

__device__ __forceinline__ unsigned short f2b(float f) {   // fp32 -> bf16 RNE
    unsigned u = __float_as_uint(f);
    u += 0x7fffu + ((u >> 16) & 1u);
    return (unsigned short)(u >> 16);
}
__device__ __forceinline__ float b2f(unsigned short h) {
    return __uint_as_float(((unsigned)h) << 16);
}

// ---------------------------------------------------------------------------
// Stage ROWS x 64 bf16 tile (row-major, 128B rows) global -> LDS via
// global_load_lds width=16, with XOR-8 chunk swizzle: global chunk c of row r
// stored at LDS slot (c ^ (r&7)). Wave-load = 8 rows (64 lanes x 16B = 1KB).
// ---------------------------------------------------------------------------
template<int ROWS>
__device__ __forceinline__ void stage_tile(unsigned short* lds,
                                           const unsigned short* g, int ld)
{
    const int tid = threadIdx.x;
    const int wave = tid >> 6, lane = tid & 63;
    constexpr int per_wave = ROWS / 32;
    #pragma unroll
    for (int i = 0; i < per_wave; ++i) {
        const int r0 = (wave * per_wave + i) * 8;
        const int r  = r0 + (lane >> 3);
        const int cg = (lane & 7) ^ (r & 7);
        const unsigned short* gp = g + (size_t)r * ld + cg * 8;
        __builtin_amdgcn_global_load_lds(
            (const __attribute__((address_space(1))) unsigned int*)(const void*)gp,
            (__attribute__((address_space(3))) unsigned int*)(void*)(lds + r0 * 64),
            16, 0, 0);
    }
}

// ---------------------------------------------------------------------------
// C(M,N) = A(M,K) @ B(N,K)^T [bf16 in, fp32 acc]. BM=128 BN=128 BK=64,
// 4 waves 2x2, each wave 64x64 = 4x4 MFMA frags. Optional bias[n],
// addrow[row&127][n], scatter (out[(b*L+t0+tl+1)*V + n]), bf16 or f32 store.
// ---------------------------------------------------------------------------
__global__ __launch_bounds__(256)
void gemm128(const unsigned short* __restrict__ A, int lda,
             const unsigned short* __restrict__ Bm, int ldb,
             float* __restrict__ OutF, unsigned short* __restrict__ OutH,
             int N, int K,
             const float* __restrict__ bias,
             const float* __restrict__ addrow,
             int scatter, int t0)
{
    __shared__ unsigned short As[128 * 64];
    __shared__ unsigned short Bs[128 * 64];
    const int tid = threadIdx.x;
    const int wave = tid >> 6, lane = tid & 63;
    const int wm = wave >> 1, wn = wave & 1;
    const int q = lane >> 4, l15 = lane & 15, l7 = lane & 7;
    const int m0 = blockIdx.y * 128, n0 = blockIdx.x * 128;
    f4v acc[4][4] = {};
    for (int kb = 0; kb < K; kb += 64) {
        stage_tile<128>(As, A + (size_t)m0 * lda + kb, lda);
        stage_tile<128>(Bs, Bm + (size_t)n0 * ldb + kb, ldb);
        __syncthreads();
        #pragma unroll
        for (int kk = 0; kk < 2; ++kk) {
            const int ch = (kk * 4 + q) ^ l7;
            s8v a[4], b[4];
            #pragma unroll
            for (int i = 0; i < 4; ++i) {
                a[i] = *(const s8v*)(As + (wm * 64 + i * 16 + l15) * 64 + ch * 8);
                b[i] = *(const s8v*)(Bs + (wn * 64 + i * 16 + l15) * 64 + ch * 8);
            }
            #pragma unroll
            for (int i = 0; i < 4; ++i)
                #pragma unroll
                for (int j = 0; j < 4; ++j)
                    acc[i][j] = __builtin_amdgcn_mfma_f32_16x16x32_bf16(
                        a[i], b[j], acc[i][j], 0, 0, 0);
        }
        __syncthreads();
    }
    #pragma unroll
    for (int i = 0; i < 4; ++i) {
        #pragma unroll
        for (int r = 0; r < 4; ++r) {
            const int row = m0 + wm * 64 + i * 16 + q * 4 + r;
            size_t obase;
            if (scatter) {
                const int bidx = row & 127, tl = row >> 7;
                obase = (size_t)(bidx * KL + t0 + tl + 1) * KV;
            } else {
                obase = (size_t)row * N;
            }
            #pragma unroll
            for (int j = 0; j < 4; ++j) {
                const int col = n0 + wn * 64 + j * 16 + l15;
                float v = acc[i][j][r];
                if (bias)   v += bias[col];
                if (addrow) v += addrow[(size_t)(row & 127) * N + col];
                if (OutF) OutF[obase + col] = v;
                else      OutH[obase + col] = f2b(v);
            }
        }
    }
}

// ---------------------------------------------------------------------------
// Lightweight grid barrier (requires cooperative launch: all 256 blocks
// resident). cnt/gen in separate 256B-apart words; monotone generation.
// ---------------------------------------------------------------------------
__device__ __forceinline__ void gridbar(unsigned* cnt, unsigned* gen)
{
    __syncthreads();
    if (threadIdx.x == 0) {
        __threadfence();   // release: drain stores + L2 writeback (cross-XCD)
        const unsigned g = __hip_atomic_load(gen, __ATOMIC_RELAXED,
                                             __HIP_MEMORY_SCOPE_AGENT);
        const unsigned a = __hip_atomic_fetch_add(cnt, 1u, __ATOMIC_ACQ_REL,
                                                  __HIP_MEMORY_SCOPE_AGENT);
        if (a == 255u) {   // gridDim.x == 256
            __hip_atomic_store(cnt, 0u, __ATOMIC_RELAXED,
                               __HIP_MEMORY_SCOPE_AGENT);
            __hip_atomic_store(gen, g + 1u, __ATOMIC_RELEASE,
                               __HIP_MEMORY_SCOPE_AGENT);
        } else {
            while (__hip_atomic_load(gen, __ATOMIC_RELAXED,
                                     __HIP_MEMORY_SCOPE_AGENT) == g)
                __builtin_amdgcn_s_sleep(2);
        }
        __threadfence();   // acquire: invalidate caches before hb reads
    }
    __syncthreads();
}

// ---------------------------------------------------------------------------
// Persistent fused recurrence: Tc GRU steps in ONE cooperative launch.
// Grid = 256 blocks x 256 thr. Block b: m0 = (b&3)*32 (batch rows),
// hc0 = (b>>2)*16 (H columns, gate-aligned: W rows {g*1024+hc0..+16}).
// W_hh slice lives in swizzled LDS for the whole chunk; h f32 patch lives in
// registers; hb (bf16 state) ping-pongs in global between grid barriers.
// gh = h @ W_hh^T split K 4-ways across waves, LDS-reduced, then fused GRU
// elementwise (gi bf16 [+ci f32] + b_hh) -> h, hb, optional h2 (featc).
// ---------------------------------------------------------------------------
__global__ __launch_bounds__(256)
void rec_fused(const unsigned short* __restrict__ gi,
               const float* __restrict__ ci,
               unsigned short* hb,               // [2][128][1024] ping-pong
               float* __restrict__ h,            // [128][1024]
               unsigned short* __restrict__ h2,  // featc+KE (ld KE+KH) or null
               const unsigned short* __restrict__ Whh,   // bf16 [3072][1024]
               const float* __restrict__ bhh,
               unsigned* bar, int Tc)
{
    __shared__ unsigned short Ws[3 * 16 * KH];   // 98304 B, XOR-8 swizzled
    __shared__ float Pp[4 * 6 * 4 * 16 * 4];     // 24576 B wave partials
    const int tid  = threadIdx.x;
    const int wave = tid >> 6, lane = tid & 63;
    const int q = lane >> 4, l15 = lane & 15;
    const int m0  = ((int)blockIdx.x & 3) * 32;
    const int hc0 = ((int)blockIdx.x >> 2) * 16;

    // ---- stage W_hh slice (48 rows x 1024 bf16) -> LDS, slot s holds
    //      global chunk s^(row&7)  (16B chunks, 128 per row) ----
    #pragma unroll
    for (int it = 0; it < 24; ++it) {
        const int gidx = it * 256 + tid;
        const int row  = gidx >> 7;            // 0..47 = g*16 + rr
        const int slot = gidx & 127;
        const int csrc = slot ^ (row & 7);
        const int g = row >> 4, rr = row & 15;
        const unsigned short* src =
            Whh + (size_t)(g * KH + hc0 + rr) * KH + csrc * 8;
        __builtin_amdgcn_global_load_lds(
            (const __attribute__((address_space(1))) unsigned int*)(const void*)src,
            (__attribute__((address_space(3))) unsigned int*)(void*)(Ws + row * KH + slot * 8),
            16, 0, 0);
    }

    // ---- per-thread persistent elementwise state ----
    const int col16 = tid & 15;
    const int rowq  = (tid >> 4) & 15;
    const int qq = rowq >> 2, r4 = rowq & 3;
    const int col = hc0 + col16;
    float bh[3], civ[2][3], hv[2];
    #pragma unroll
    for (int g = 0; g < 3; ++g) bh[g] = bhh[g * KH + col];
    #pragma unroll
    for (int i = 0; i < 2; ++i) {
        const int row = m0 + i * 16 + rowq;
        hv[i] = h[(size_t)row * KH + col];
        #pragma unroll
        for (int g = 0; g < 3; ++g)
            civ[i][g] = ci ? ci[(size_t)row * KH3 + g * KH + col] : 0.0f;
    }
    __syncthreads();   // Ws staged (vmcnt drained by barrier)

    int cur = 0;
    for (int tl = 0; tl < Tc; ++tl) {
        const unsigned short* hin = hb + (size_t)cur * KB * KH;
        // A fragments direct from global: row = m0+i*16+l15,
        // k = wave*256 + kk*32 + q*8 (matches 16x16x32 bf16 A layout)
        s8v a[2][8];
        #pragma unroll
        for (int i = 0; i < 2; ++i)
            #pragma unroll
            for (int kk = 0; kk < 8; ++kk)
                a[i][kk] = *(const s8v*)(hin +
                    (size_t)(m0 + i * 16 + l15) * KH + wave * 256 + kk * 32 + q * 8);
        f4v acc[2][3] = {};
        #pragma unroll
        for (int kk = 0; kk < 8; ++kk) {
            const int soff = ((wave * 32 + kk * 4 + q) ^ (l15 & 7)) * 8;
            #pragma unroll
            for (int g = 0; g < 3; ++g) {
                const s8v bf = *(const s8v*)(Ws + (g * 16 + l15) * KH + soff);
                acc[0][g] = __builtin_amdgcn_mfma_f32_16x16x32_bf16(
                    a[0][kk], bf, acc[0][g], 0, 0, 0);
                acc[1][g] = __builtin_amdgcn_mfma_f32_16x16x32_bf16(
                    a[1][kk], bf, acc[1][g], 0, 0, 0);
            }
        }
        // wave partials -> LDS (D layout: reg r = row q*4+r, col l15)
        #pragma unroll
        for (int i = 0; i < 2; ++i)
            #pragma unroll
            for (int g = 0; g < 3; ++g)
                *(f4v*)(Pp + (((wave * 6 + i * 3 + g) * 4 + q) * 16 + l15) * 4)
                    = acc[i][g];
        __syncthreads();
        // reduce 4 waves + fused GRU elementwise
        unsigned short* hout = hb + (size_t)(cur ^ 1) * KB * KH;
        #pragma unroll
        for (int i = 0; i < 2; ++i) {
            float gs0 = 0.f, gs1 = 0.f, gs2 = 0.f;
            #pragma unroll
            for (int w = 0; w < 4; ++w) {
                const float* p = Pp + ((w * 6 + i * 3) * 4 + qq) * 64
                               + col16 * 4 + r4;
                gs0 += p[0]; gs1 += p[256]; gs2 += p[512];
            }
            const int row = m0 + i * 16 + rowq;
            const size_t gib = ((size_t)tl * KB + row) * KH3 + col;
            const float ir  = b2f(gi[gib])          + civ[i][0];
            const float iz  = b2f(gi[gib + KH])     + civ[i][1];
            const float in_ = b2f(gi[gib + 2 * KH]) + civ[i][2];
            const float rg = 1.0f / (1.0f + __expf(-(ir + gs0 + bh[0])));
            const float zg = 1.0f / (1.0f + __expf(-(iz + gs1 + bh[1])));
            const float ng = tanhf(in_ + rg * (gs2 + bh[2]));
            hv[i] = (1.0f - zg) * ng + zg * hv[i];
            const unsigned short hb16 = f2b(hv[i]);
            hout[(size_t)row * KH + col] = hb16;
            if (h2) h2[((size_t)tl * KB + row) * (KE + KH) + col] = hb16;
        }
        if (tl + 1 < Tc) gridbar(bar, bar + 64);  // last step: kernel-end sync
        cur ^= 1;
    }
    // write back f32 h patch (context for ctx copy / next chunk)
    #pragma unroll
    for (int i = 0; i < 2; ++i)
        h[(size_t)(m0 + i * 16 + rowq) * KH + col] = hv[i];
}

static void launch_rec(const unsigned short* gi, const float* ci,
                       unsigned short* hb, float* h, unsigned short* h2,
                       const unsigned short* Whh, const float* bhh,
                       unsigned* bar, int Tc, hipStream_t stream)
{
    void* args[9] = { (void*)&gi, (void*)&ci, (void*)&hb, (void*)&h,
                      (void*)&h2, (void*)&Whh, (void*)&bhh, (void*)&bar,
                      (void*)&Tc };
    hipLaunchCooperativeKernel((const void*)rec_fused, dim3(256), dim3(256),
                               args, 0, stream);
}

// X[tl*128+b, 0:512] = bf16(emb[seq[b, t0+tl], :]), row stride ldx
__global__ __launch_bounds__(256)
void gather_emb(const float* __restrict__ emb, const int* __restrict__ seq,
                unsigned short* __restrict__ X, int ldx, int t0)
{
    const int idx = blockIdx.x * 256 + threadIdx.x;   // Tc*B*64
    const int e8 = idx & 63;
    const int rr = idx >> 6;
    const int b = rr & 127, tl = rr >> 7;
    const int tok = seq[b * KL + t0 + tl];
    const float4* src = (const float4*)(emb + (size_t)tok * KE + e8 * 8);
    const float4 v0 = src[0], v1 = src[1];
    u16x8 o;
    o[0] = f2b(v0.x); o[1] = f2b(v0.y); o[2] = f2b(v0.z); o[3] = f2b(v0.w);
    o[4] = f2b(v1.x); o[5] = f2b(v1.y); o[6] = f2b(v1.z); o[7] = f2b(v1.w);
    *(u16x8*)(X + (size_t)rr * ldx + e8 * 8) = o;
}

__global__ __launch_bounds__(256)
void f32tobf16(const float* __restrict__ src, unsigned short* __restrict__ dst, int n)
{
    const int i = (blockIdx.x * 256 + threadIdx.x) * 4;
    if (i < n) {
        const float4 v = *(const float4*)(src + i);
        dst[i] = f2b(v.x); dst[i + 1] = f2b(v.y);
        dst[i + 2] = f2b(v.z); dst[i + 3] = f2b(v.w);
    }
}

__global__ __launch_bounds__(256)
void zero_f32(float* __restrict__ p, int n)
{
    const int i = blockIdx.x * 256 + threadIdx.x;
    if (i < n) p[i] = 0.0f;
}

__global__ __launch_bounds__(256)
void zero_u16(unsigned short* __restrict__ p, int n)
{
    const int i = blockIdx.x * 256 + threadIdx.x;
    if (i < n) p[i] = 0;
}

__global__ __launch_bounds__(256)
void copy_f32(float* __restrict__ dst, const float* __restrict__ src, int n)
{
    const int i = blockIdx.x * 256 + threadIdx.x;
    if (i < n) dst[i] = src[i];
}

__global__ __launch_bounds__(256)
void zero_row0(float* __restrict__ out)
{
    const int idx = blockIdx.x * 256 + threadIdx.x;   // B*V
    const int b = idx >> 11, v = idx & (KV - 1);
    out[(size_t)b * KL * KV + v] = 0.0f;
}

extern "C" void kernel_launch(void* const* d_in, const int* in_sizes, int n_in,
                              void* d_out, int out_size, void* d_ws, size_t ws_size,
                              hipStream_t stream)
{
    (void)in_sizes; (void)n_in; (void)out_size; (void)ws_size;
    const int*   seq     = (const int*)  d_in[0];
    const float* emb_enc = (const float*)d_in[2];
    const float* W_ih_e  = (const float*)d_in[3];
    const float* W_hh_e  = (const float*)d_in[4];
    const float* b_ih_e  = (const float*)d_in[5];
    const float* b_hh_e  = (const float*)d_in[6];
    const float* emb_dec = (const float*)d_in[7];
    const float* W_ih_d  = (const float*)d_in[8];   // (3H, E+H)
    const float* W_hh_d  = (const float*)d_in[9];
    const float* b_ih_d  = (const float*)d_in[10];
    const float* b_hh_d  = (const float*)d_in[11];
    const float* fc_W    = (const float*)d_in[12];  // (V, E+2H)
    const float* fc_b    = (const float*)d_in[13];
    float* out = (float*)d_out;

    // ---- workspace layout (~81.3 MB) ----
    char* w = (char*)d_ws;
    unsigned*       bar     = (unsigned*)w;                  w += 512;
    unsigned short* Wb_ih_e = (unsigned short*)w;            w += (size_t)KH3 * KE * 2;
    unsigned short* Wb_hh_e = (unsigned short*)w;            w += (size_t)KH3 * KH * 2;
    unsigned short* Wb_ih_d = (unsigned short*)w;            w += (size_t)KH3 * (KE + KH) * 2;
    unsigned short* Wb_hh_d = (unsigned short*)w;            w += (size_t)KH3 * KH * 2;
    unsigned short* fc_Wb   = (unsigned short*)w;            w += (size_t)KV * (KE + 2 * KH) * 2;
    float*          h       = (float*)w;                     w += (size_t)KB * KH * 4;
    unsigned short* hb      = (unsigned short*)w;            w += (size_t)2 * KB * KH * 2;  // ping-pong
    float*          ci      = (float*)w;                     w += (size_t)KB * KH3 * 4;
    float*          cf      = (float*)w;                     w += (size_t)KB * KV * 4;
    unsigned short* gi      = (unsigned short*)w;            w += (size_t)TCH * KB * KH3 * 2;
    unsigned short* featc   = (unsigned short*)w;            w += (size_t)TCH * KB * (KE + KH) * 2;

    // ---- weight conversion to bf16 ----
    f32tobf16<<<(KH3 * KE) / 1024, 256, 0, stream>>>(W_ih_e, Wb_ih_e, KH3 * KE);
    f32tobf16<<<(KH3 * KH) / 1024, 256, 0, stream>>>(W_hh_e, Wb_hh_e, KH3 * KH);
    f32tobf16<<<(KH3 * (KE + KH)) / 1024, 256, 0, stream>>>(W_ih_d, Wb_ih_d, KH3 * (KE + KH));
    f32tobf16<<<(KH3 * KH) / 1024, 256, 0, stream>>>(W_hh_d, Wb_hh_d, KH3 * KH);
    f32tobf16<<<(KV * (KE + 2 * KH)) / 1024, 256, 0, stream>>>(fc_W, fc_Wb, KV * (KE + 2 * KH));

    zero_f32<<<1, 256, 0, stream>>>((float*)bar, 128);
    zero_f32<<<(KB * KH) / 256, 256, 0, stream>>>(h, KB * KH);
    zero_u16<<<(2 * KB * KH) / 256, 256, 0, stream>>>(hb, 2 * KB * KH);

    // ---------------- Encoder ----------------
    for (int t0 = 0; t0 < KL; t0 += TCH) {
        unsigned short* Xc = featc;   // bf16 embeddings staging, ld=512
        gather_emb<<<(TCH * KB * 64) / 256, 256, 0, stream>>>(emb_enc, seq, Xc, KE, t0);
        // gi = Xc @ W_ih_e^T + b_ih_e   (M=4096, N=3072, K=512) -> bf16
        gemm128<<<dim3(KH3 / 128, (TCH * KB) / 128), 256, 0, stream>>>(
            Xc, KE, Wb_ih_e, KE, nullptr, gi, KH3, KE, b_ih_e, nullptr, 0, 0);
        // 32 recurrent steps in one cooperative launch
        launch_rec(gi, nullptr, hb, h, nullptr, Wb_hh_e, b_hh_e, bar, TCH, stream);
    }

    // context -> d_out; mu = log_var = 0; outputs[:,0,:] = 0
    float* ctx_out = out + (size_t)KB * KL * KV;
    copy_f32<<<(KB * KH) / 256, 256, 0, stream>>>(ctx_out, h, KB * KH);
    zero_f32<<<(2 * KB * KH) / 256, 256, 0, stream>>>(ctx_out + KB * KH, 2 * KB * KH);
    zero_row0<<<(KB * KV) / 256, 256, 0, stream>>>(out);

    // ci = context @ W_ih_d[:, E:]^T + b_ih_d   (M=128, N=3072, K=1024)
    gemm128<<<dim3(KH3 / 128, 1), 256, 0, stream>>>(
        hb, KH, Wb_ih_d + KE, KE + KH, ci, nullptr, KH3, KH, b_ih_d, nullptr, 0, 0);
    // cf = context @ fc_W[:, E+H:]^T + fc_b     (M=128, N=2048, K=1024)
    gemm128<<<dim3(KV / 128, 1), 256, 0, stream>>>(
        hb, KH, fc_Wb + (KE + KH), KE + 2 * KH, cf, nullptr, KV, KH, fc_b, nullptr, 0, 0);

    // ---------------- Decoder ---------------- (h/hb[0] currently = context)
    for (int t0 = 0; t0 < KL - 1; t0 += TCH) {
        const int Tc = ((KL - 1 - t0) < TCH) ? (KL - 1 - t0) : TCH;
        // featc rows (tl*128+b): cols [0,512) = e_t, cols [512,1536) = h2
        gather_emb<<<(Tc * KB * 64) / 256, 256, 0, stream>>>(emb_dec, seq, featc, KE + KH, t0);
        // gi = e @ W_ih_d[:, :E]^T  (bias lives in ci) -> bf16
        gemm128<<<dim3(KH3 / 128, (Tc * KB) / 128), 256, 0, stream>>>(
            featc, KE + KH, Wb_ih_d, KE + KH, nullptr, gi, KH3, KE, nullptr, nullptr, 0, 0);
        // Tc recurrent steps (writes h2 into featc cols [512,1536))
        launch_rec(gi, ci, hb, h, featc + KE, Wb_hh_d, b_hh_d, bar, Tc, stream);
        // preds = [e, h2] @ fc_W[:, :E+H]^T + cf  (K=1536, scatter rows t0+tl+1)
        gemm128<<<dim3(KV / 128, (Tc * KB) / 128), 256, 0, stream>>>(
            featc, KE + KH, fc_Wb, KE + 2 * KH, out, nullptr, KV, KE + KH,
            nullptr, cf, 1, t0);
    }
}

// Round 2
// 6105.157 us; speedup vs baseline: 1.8987x; 1.8987x over previous
//
#include <hip/hip_runtime.h>
#include <math.h>

#define KV 2048
#define KE 512
#define KH 1024
#define KB 128
#define KL 256
#define KH3 3072
#define TCH 32

typedef __attribute__((ext_vector_type(8))) short s8v;     // 8 bf16 (4 VGPRs)
typedef __attribute__((ext_vector_type(8))) unsigned short u16x8;
typedef __attribute__((ext_vector_type(4))) float f4v;

__device__ __forceinline__ unsigned short f2b(float f) {   // fp32 -> bf16 RNE
    unsigned u = __float_as_uint(f);
    u += 0x7fffu + ((u >> 16) & 1u);
    return (unsigned short)(u >> 16);
}
__device__ __forceinline__ float b2f(unsigned short h) {
    return __uint_as_float(((unsigned)h) << 16);
}

// ---------------------------------------------------------------------------
// Stage ROWS x 64 bf16 tile (row-major, 128B rows) global -> LDS via
// global_load_lds width=16, with XOR-8 chunk swizzle: global chunk c of row r
// stored at LDS slot (c ^ (r&7)). Wave-load = 8 rows (64 lanes x 16B = 1KB).
// ---------------------------------------------------------------------------
template<int ROWS>
__device__ __forceinline__ void stage_tile(unsigned short* lds,
                                           const unsigned short* g, int ld)
{
    const int tid = threadIdx.x;
    const int wave = tid >> 6, lane = tid & 63;
    constexpr int per_wave = ROWS / 32;
    #pragma unroll
    for (int i = 0; i < per_wave; ++i) {
        const int r0 = (wave * per_wave + i) * 8;
        const int r  = r0 + (lane >> 3);
        const int cg = (lane & 7) ^ (r & 7);
        const unsigned short* gp = g + (size_t)r * ld + cg * 8;
        __builtin_amdgcn_global_load_lds(
            (const __attribute__((address_space(1))) unsigned int*)(const void*)gp,
            (__attribute__((address_space(3))) unsigned int*)(void*)(lds + r0 * 64),
            16, 0, 0);
    }
}

// ---------------------------------------------------------------------------
// C(M,N) = A(M,K) @ B(N,K)^T [bf16 in, fp32 acc]. BM=128 BN=128 BK=64,
// 4 waves 2x2, each wave 64x64 = 4x4 MFMA frags. Optional bias[n],
// addrow[row&127][n], scatter (out[(b*L+t0+tl+1)*V + n]), bf16 or f32 store.
// ---------------------------------------------------------------------------
__global__ __launch_bounds__(256)
void gemm128(const unsigned short* __restrict__ A, int lda,
             const unsigned short* __restrict__ Bm, int ldb,
             float* __restrict__ OutF, unsigned short* __restrict__ OutH,
             int N, int K,
             const float* __restrict__ bias,
             const float* __restrict__ addrow,
             int scatter, int t0)
{
    __shared__ unsigned short As[128 * 64];
    __shared__ unsigned short Bs[128 * 64];
    const int tid = threadIdx.x;
    const int wave = tid >> 6, lane = tid & 63;
    const int wm = wave >> 1, wn = wave & 1;
    const int q = lane >> 4, l15 = lane & 15, l7 = lane & 7;
    const int m0 = blockIdx.y * 128, n0 = blockIdx.x * 128;
    f4v acc[4][4] = {};
    for (int kb = 0; kb < K; kb += 64) {
        stage_tile<128>(As, A + (size_t)m0 * lda + kb, lda);
        stage_tile<128>(Bs, Bm + (size_t)n0 * ldb + kb, ldb);
        __syncthreads();
        #pragma unroll
        for (int kk = 0; kk < 2; ++kk) {
            const int ch = (kk * 4 + q) ^ l7;
            s8v a[4], b[4];
            #pragma unroll
            for (int i = 0; i < 4; ++i) {
                a[i] = *(const s8v*)(As + (wm * 64 + i * 16 + l15) * 64 + ch * 8);
                b[i] = *(const s8v*)(Bs + (wn * 64 + i * 16 + l15) * 64 + ch * 8);
            }
            #pragma unroll
            for (int i = 0; i < 4; ++i)
                #pragma unroll
                for (int j = 0; j < 4; ++j)
                    acc[i][j] = __builtin_amdgcn_mfma_f32_16x16x32_bf16(
                        a[i], b[j], acc[i][j], 0, 0, 0);
        }
        __syncthreads();
    }
    #pragma unroll
    for (int i = 0; i < 4; ++i) {
        #pragma unroll
        for (int r = 0; r < 4; ++r) {
            const int row = m0 + wm * 64 + i * 16 + q * 4 + r;
            size_t obase;
            if (scatter) {
                const int bidx = row & 127, tl = row >> 7;
                obase = (size_t)(bidx * KL + t0 + tl + 1) * KV;
            } else {
                obase = (size_t)row * N;
            }
            #pragma unroll
            for (int j = 0; j < 4; ++j) {
                const int col = n0 + wn * 64 + j * 16 + l15;
                float v = acc[i][j][r];
                if (bias)   v += bias[col];
                if (addrow) v += addrow[(size_t)(row & 127) * N + col];
                if (OutF) OutF[obase + col] = v;
                else      OutH[obase + col] = f2b(v);
            }
        }
    }
}

// ---------------------------------------------------------------------------
// Persistent fused recurrence: Tc GRU steps in ONE cooperative launch.
// Grid = 256 blocks x 256 thr. Block b: m0 = (b&3)*32 (batch rows),
// hc0 = (b>>2)*16 (H columns, gate-aligned: W rows {g*1024+hc0..+16}).
// W_hh slice lives in swizzled LDS for the whole chunk; h f32 patch lives in
// registers; hb (bf16 state) ping-pongs in global between steps.
//
// Cross-block coherence WITHOUT L2 flushes: all hb traffic and the step
// flags use per-instruction sc0 sc1 cache bits (bypass L1+L2, served at the
// device coherence point / LLC). Signal protocol per step: stores ->
// s_waitcnt vmcnt(0) -> __syncthreads -> tid0 stores flags[bid] = gen0+tl+1
// (monotone across launches, so no resets) -> all 256 threads poll one flag
// each until >= target -> __syncthreads. No atomics, no buffer_wbl2/inv.
// ---------------------------------------------------------------------------
__global__ __launch_bounds__(256)
void rec_fused(const unsigned short* __restrict__ gi,
               const float* __restrict__ ci,
               unsigned short* hb,               // [2][128][1024] ping-pong
               float* __restrict__ h,            // [128][1024]
               unsigned short* __restrict__ h2,  // featc+KE (ld KE+KH) or null
               const unsigned short* __restrict__ Whh,   // bf16 [3072][1024]
               const float* __restrict__ bhh,
               unsigned* bar, int Tc, unsigned gen0)
{
    __shared__ unsigned short Ws[3 * 16 * KH];   // 98304 B, XOR-8 swizzled
    __shared__ float Pp[4 * 6 * 4 * 16 * 4];     // 24576 B wave partials
    unsigned* flags = bar + 64;                  // 256 entries
    const int tid  = threadIdx.x;
    const int wave = tid >> 6, lane = tid & 63;
    const int q = lane >> 4, l15 = lane & 15;
    const int m0  = ((int)blockIdx.x & 3) * 32;
    const int hc0 = ((int)blockIdx.x >> 2) * 16;

    // ---- stage W_hh slice (48 rows x 1024 bf16) -> LDS, slot s holds
    //      global chunk s^(row&7)  (16B chunks, 128 per row) ----
    #pragma unroll
    for (int it = 0; it < 24; ++it) {
        const int gidx = it * 256 + tid;
        const int row  = gidx >> 7;            // 0..47 = g*16 + rr
        const int slot = gidx & 127;
        const int csrc = slot ^ (row & 7);
        const int g = row >> 4, rr = row & 15;
        const unsigned short* src =
            Whh + (size_t)(g * KH + hc0 + rr) * KH + csrc * 8;
        __builtin_amdgcn_global_load_lds(
            (const __attribute__((address_space(1))) unsigned int*)(const void*)src,
            (__attribute__((address_space(3))) unsigned int*)(void*)(Ws + row * KH + slot * 8),
            16, 0, 0);
    }

    // ---- per-thread persistent elementwise state ----
    const int col16 = tid & 15;
    const int rowq  = (tid >> 4) & 15;
    const int qq = rowq >> 2, r4 = rowq & 3;
    const int col = hc0 + col16;
    float bh[3], civ[2][3], hv[2];
    #pragma unroll
    for (int g = 0; g < 3; ++g) bh[g] = bhh[g * KH + col];
    #pragma unroll
    for (int i = 0; i < 2; ++i) {
        const int row = m0 + i * 16 + rowq;
        hv[i] = h[(size_t)row * KH + col];
        #pragma unroll
        for (int g = 0; g < 3; ++g)
            civ[i][g] = ci ? ci[(size_t)row * KH3 + g * KH + col] : 0.0f;
    }
    __syncthreads();   // Ws staged (barrier drains vmcnt)

    int cur = 0;
    for (int tl = 0; tl < Tc; ++tl) {
        const unsigned short* hin = hb + (size_t)cur * KB * KH;
        // A fragments direct from coherence point (sc0 sc1), 16 loads in one
        // asm with the vmcnt(0) inside (keeps MFMA consumers ordered).
        // a[i][kk] = hin[(m0+i*16+l15)*KH + wave*256 + kk*32 + q*8]
        const unsigned short* p0 = hin + (size_t)(m0 + l15) * KH + wave * 256 + q * 8;
        const unsigned short* p1 = p0 + 16 * KH;
        s8v a0, a1, a2, a3, a4, a5, a6, a7, b0, b1, b2, b3, b4, b5, b6, b7;
        asm volatile(
            "global_load_dwordx4 %0, %16, off sc0 sc1\n\t"
            "global_load_dwordx4 %1, %16, off offset:64 sc0 sc1\n\t"
            "global_load_dwordx4 %2, %16, off offset:128 sc0 sc1\n\t"
            "global_load_dwordx4 %3, %16, off offset:192 sc0 sc1\n\t"
            "global_load_dwordx4 %4, %16, off offset:256 sc0 sc1\n\t"
            "global_load_dwordx4 %5, %16, off offset:320 sc0 sc1\n\t"
            "global_load_dwordx4 %6, %16, off offset:384 sc0 sc1\n\t"
            "global_load_dwordx4 %7, %16, off offset:448 sc0 sc1\n\t"
            "global_load_dwordx4 %8, %17, off sc0 sc1\n\t"
            "global_load_dwordx4 %9, %17, off offset:64 sc0 sc1\n\t"
            "global_load_dwordx4 %10, %17, off offset:128 sc0 sc1\n\t"
            "global_load_dwordx4 %11, %17, off offset:192 sc0 sc1\n\t"
            "global_load_dwordx4 %12, %17, off offset:256 sc0 sc1\n\t"
            "global_load_dwordx4 %13, %17, off offset:320 sc0 sc1\n\t"
            "global_load_dwordx4 %14, %17, off offset:384 sc0 sc1\n\t"
            "global_load_dwordx4 %15, %17, off offset:448 sc0 sc1\n\t"
            "s_waitcnt vmcnt(0)"
            : "=&v"(a0), "=&v"(a1), "=&v"(a2), "=&v"(a3),
              "=&v"(a4), "=&v"(a5), "=&v"(a6), "=&v"(a7),
              "=&v"(b0), "=&v"(b1), "=&v"(b2), "=&v"(b3),
              "=&v"(b4), "=&v"(b5), "=&v"(b6), "=&v"(b7)
            : "v"(p0), "v"(p1)
            : "memory");
        s8v a[2][8] = {{a0, a1, a2, a3, a4, a5, a6, a7},
                       {b0, b1, b2, b3, b4, b5, b6, b7}};
        f4v acc[2][3] = {};
        #pragma unroll
        for (int kk = 0; kk < 8; ++kk) {
            const int soff = ((wave * 32 + kk * 4 + q) ^ (l15 & 7)) * 8;
            #pragma unroll
            for (int g = 0; g < 3; ++g) {
                const s8v bf = *(const s8v*)(Ws + (g * 16 + l15) * KH + soff);
                acc[0][g] = __builtin_amdgcn_mfma_f32_16x16x32_bf16(
                    a[0][kk], bf, acc[0][g], 0, 0, 0);
                acc[1][g] = __builtin_amdgcn_mfma_f32_16x16x32_bf16(
                    a[1][kk], bf, acc[1][g], 0, 0, 0);
            }
        }
        // wave partials -> LDS (D layout: reg r = row q*4+r, col l15)
        #pragma unroll
        for (int i = 0; i < 2; ++i)
            #pragma unroll
            for (int g = 0; g < 3; ++g)
                *(f4v*)(Pp + (((wave * 6 + i * 3 + g) * 4 + q) * 16 + l15) * 4)
                    = acc[i][g];
        __syncthreads();
        // reduce 4 waves + fused GRU elementwise
        unsigned short* hout = hb + (size_t)(cur ^ 1) * KB * KH;
        #pragma unroll
        for (int i = 0; i < 2; ++i) {
            float gs0 = 0.f, gs1 = 0.f, gs2 = 0.f;
            #pragma unroll
            for (int w = 0; w < 4; ++w) {
                const float* p = Pp + ((w * 6 + i * 3) * 4 + qq) * 64
                               + col16 * 4 + r4;
                gs0 += p[0]; gs1 += p[256]; gs2 += p[512];
            }
            const int row = m0 + i * 16 + rowq;
            const size_t gib = ((size_t)tl * KB + row) * KH3 + col;
            const float ir  = b2f(gi[gib])          + civ[i][0];
            const float iz  = b2f(gi[gib + KH])     + civ[i][1];
            const float in_ = b2f(gi[gib + 2 * KH]) + civ[i][2];
            const float rg = 1.0f / (1.0f + __expf(-(ir + gs0 + bh[0])));
            const float zg = 1.0f / (1.0f + __expf(-(iz + gs1 + bh[1])));
            const float ng = tanhf(in_ + rg * (gs2 + bh[2]));
            hv[i] = (1.0f - zg) * ng + zg * hv[i];
            const unsigned short hb16 = f2b(hv[i]);
            const unsigned short* sp = hout + (size_t)row * KH + col;
            const unsigned hval = hb16;
            asm volatile("global_store_short %0, %1, off sc0 sc1"
                         :: "v"(sp), "v"(hval) : "memory");
            if (h2) h2[((size_t)tl * KB + row) * (KE + KH) + col] = hb16;
        }
        if (tl + 1 < Tc) {
            const unsigned tgt = gen0 + (unsigned)tl + 1u;
            asm volatile("s_waitcnt vmcnt(0)" ::: "memory");   // hb stores at LLC
            __syncthreads();                                   // whole block done
            if (tid == 0) {
                const unsigned* fp = flags + blockIdx.x;
                asm volatile("global_store_dword %0, %1, off sc0 sc1"
                             :: "v"(fp), "v"(tgt) : "memory");
            }
            const unsigned* fp = flags + tid;                  // poll block tid
            unsigned v;
            while (true) {
                asm volatile("global_load_dword %0, %1, off sc0 sc1\n\t"
                             "s_waitcnt vmcnt(0)"
                             : "=v"(v) : "v"(fp) : "memory");
                if (v >= tgt) break;
                __builtin_amdgcn_s_sleep(1);
            }
            __syncthreads();
        }
        cur ^= 1;
    }
    // write back f32 h patch (context for ctx copy / next chunk)
    #pragma unroll
    for (int i = 0; i < 2; ++i)
        h[(size_t)(m0 + i * 16 + rowq) * KH + col] = hv[i];
}

static void launch_rec(const unsigned short* gi, const float* ci,
                       unsigned short* hb, float* h, unsigned short* h2,
                       const unsigned short* Whh, const float* bhh,
                       unsigned* bar, int Tc, unsigned gen0, hipStream_t stream)
{
    void* args[10] = { (void*)&gi, (void*)&ci, (void*)&hb, (void*)&h,
                       (void*)&h2, (void*)&Whh, (void*)&bhh, (void*)&bar,
                       (void*)&Tc, (void*)&gen0 };
    hipLaunchCooperativeKernel((const void*)rec_fused, dim3(256), dim3(256),
                               args, 0, stream);
}

// X[tl*128+b, 0:512] = bf16(emb[seq[b, t0+tl], :]), row stride ldx
__global__ __launch_bounds__(256)
void gather_emb(const float* __restrict__ emb, const int* __restrict__ seq,
                unsigned short* __restrict__ X, int ldx, int t0)
{
    const int idx = blockIdx.x * 256 + threadIdx.x;   // Tc*B*64
    const int e8 = idx & 63;
    const int rr = idx >> 6;
    const int b = rr & 127, tl = rr >> 7;
    const int tok = seq[b * KL + t0 + tl];
    const float4* src = (const float4*)(emb + (size_t)tok * KE + e8 * 8);
    const float4 v0 = src[0], v1 = src[1];
    u16x8 o;
    o[0] = f2b(v0.x); o[1] = f2b(v0.y); o[2] = f2b(v0.z); o[3] = f2b(v0.w);
    o[4] = f2b(v1.x); o[5] = f2b(v1.y); o[6] = f2b(v1.z); o[7] = f2b(v1.w);
    *(u16x8*)(X + (size_t)rr * ldx + e8 * 8) = o;
}

__global__ __launch_bounds__(256)
void f32tobf16(const float* __restrict__ src, unsigned short* __restrict__ dst, int n)
{
    const int i = (blockIdx.x * 256 + threadIdx.x) * 4;
    if (i < n) {
        const float4 v = *(const float4*)(src + i);
        dst[i] = f2b(v.x); dst[i + 1] = f2b(v.y);
        dst[i + 2] = f2b(v.z); dst[i + 3] = f2b(v.w);
    }
}

__global__ __launch_bounds__(256)
void zero_f32(float* __restrict__ p, int n)
{
    const int i = blockIdx.x * 256 + threadIdx.x;
    if (i < n) p[i] = 0.0f;
}

__global__ __launch_bounds__(256)
void zero_u16(unsigned short* __restrict__ p, int n)
{
    const int i = blockIdx.x * 256 + threadIdx.x;
    if (i < n) p[i] = 0;
}

__global__ __launch_bounds__(256)
void copy_f32(float* __restrict__ dst, const float* __restrict__ src, int n)
{
    const int i = blockIdx.x * 256 + threadIdx.x;
    if (i < n) dst[i] = src[i];
}

__global__ __launch_bounds__(256)
void zero_row0(float* __restrict__ out)
{
    const int idx = blockIdx.x * 256 + threadIdx.x;   // B*V
    const int b = idx >> 11, v = idx & (KV - 1);
    out[(size_t)b * KL * KV + v] = 0.0f;
}

extern "C" void kernel_launch(void* const* d_in, const int* in_sizes, int n_in,
                              void* d_out, int out_size, void* d_ws, size_t ws_size,
                              hipStream_t stream)
{
    (void)in_sizes; (void)n_in; (void)out_size; (void)ws_size;
    const int*   seq     = (const int*)  d_in[0];
    const float* emb_enc = (const float*)d_in[2];
    const float* W_ih_e  = (const float*)d_in[3];
    const float* W_hh_e  = (const float*)d_in[4];
    const float* b_ih_e  = (const float*)d_in[5];
    const float* b_hh_e  = (const float*)d_in[6];
    const float* emb_dec = (const float*)d_in[7];
    const float* W_ih_d  = (const float*)d_in[8];   // (3H, E+H)
    const float* W_hh_d  = (const float*)d_in[9];
    const float* b_ih_d  = (const float*)d_in[10];
    const float* b_hh_d  = (const float*)d_in[11];
    const float* fc_W    = (const float*)d_in[12];  // (V, E+2H)
    const float* fc_b    = (const float*)d_in[13];
    float* out = (float*)d_out;

    // ---- workspace layout (~81.3 MB) ----
    char* w = (char*)d_ws;
    unsigned*       bar     = (unsigned*)w;                  w += 2048;
    unsigned short* Wb_ih_e = (unsigned short*)w;            w += (size_t)KH3 * KE * 2;
    unsigned short* Wb_hh_e = (unsigned short*)w;            w += (size_t)KH3 * KH * 2;
    unsigned short* Wb_ih_d = (unsigned short*)w;            w += (size_t)KH3 * (KE + KH) * 2;
    unsigned short* Wb_hh_d = (unsigned short*)w;            w += (size_t)KH3 * KH * 2;
    unsigned short* fc_Wb   = (unsigned short*)w;            w += (size_t)KV * (KE + 2 * KH) * 2;
    float*          h       = (float*)w;                     w += (size_t)KB * KH * 4;
    unsigned short* hb      = (unsigned short*)w;            w += (size_t)2 * KB * KH * 2;  // ping-pong
    float*          ci      = (float*)w;                     w += (size_t)KB * KH3 * 4;
    float*          cf      = (float*)w;                     w += (size_t)KB * KV * 4;
    unsigned short* gi      = (unsigned short*)w;            w += (size_t)TCH * KB * KH3 * 2;
    unsigned short* featc   = (unsigned short*)w;            w += (size_t)TCH * KB * (KE + KH) * 2;

    // ---- weight conversion to bf16 ----
    f32tobf16<<<(KH3 * KE) / 1024, 256, 0, stream>>>(W_ih_e, Wb_ih_e, KH3 * KE);
    f32tobf16<<<(KH3 * KH) / 1024, 256, 0, stream>>>(W_hh_e, Wb_hh_e, KH3 * KH);
    f32tobf16<<<(KH3 * (KE + KH)) / 1024, 256, 0, stream>>>(W_ih_d, Wb_ih_d, KH3 * (KE + KH));
    f32tobf16<<<(KH3 * KH) / 1024, 256, 0, stream>>>(W_hh_d, Wb_hh_d, KH3 * KH);
    f32tobf16<<<(KV * (KE + 2 * KH)) / 1024, 256, 0, stream>>>(fc_W, fc_Wb, KV * (KE + 2 * KH));

    zero_f32<<<2, 256, 0, stream>>>((float*)bar, 512);       // flags = 0
    zero_f32<<<(KB * KH) / 256, 256, 0, stream>>>(h, KB * KH);
    zero_u16<<<(2 * KB * KH) / 256, 256, 0, stream>>>(hb, 2 * KB * KH);

    unsigned gen0 = 0;

    // ---------------- Encoder ----------------
    for (int t0 = 0; t0 < KL; t0 += TCH) {
        unsigned short* Xc = featc;   // bf16 embeddings staging, ld=512
        gather_emb<<<(TCH * KB * 64) / 256, 256, 0, stream>>>(emb_enc, seq, Xc, KE, t0);
        // gi = Xc @ W_ih_e^T + b_ih_e   (M=4096, N=3072, K=512) -> bf16
        gemm128<<<dim3(KH3 / 128, (TCH * KB) / 128), 256, 0, stream>>>(
            Xc, KE, Wb_ih_e, KE, nullptr, gi, KH3, KE, b_ih_e, nullptr, 0, 0);
        // 32 recurrent steps in one cooperative launch
        launch_rec(gi, nullptr, hb, h, nullptr, Wb_hh_e, b_hh_e, bar, TCH, gen0, stream);
        gen0 += TCH;
    }

    // context -> d_out; mu = log_var = 0; outputs[:,0,:] = 0
    float* ctx_out = out + (size_t)KB * KL * KV;
    copy_f32<<<(KB * KH) / 256, 256, 0, stream>>>(ctx_out, h, KB * KH);
    zero_f32<<<(2 * KB * KH) / 256, 256, 0, stream>>>(ctx_out + KB * KH, 2 * KB * KH);
    zero_row0<<<(KB * KV) / 256, 256, 0, stream>>>(out);

    // ci = context @ W_ih_d[:, E:]^T + b_ih_d   (M=128, N=3072, K=1024)
    gemm128<<<dim3(KH3 / 128, 1), 256, 0, stream>>>(
        hb, KH, Wb_ih_d + KE, KE + KH, ci, nullptr, KH3, KH, b_ih_d, nullptr, 0, 0);
    // cf = context @ fc_W[:, E+H:]^T + fc_b     (M=128, N=2048, K=1024)
    gemm128<<<dim3(KV / 128, 1), 256, 0, stream>>>(
        hb, KH, fc_Wb + (KE + KH), KE + 2 * KH, cf, nullptr, KV, KH, fc_b, nullptr, 0, 0);

    // ---------------- Decoder ---------------- (h/hb[0] currently = context)
    for (int t0 = 0; t0 < KL - 1; t0 += TCH) {
        const int Tc = ((KL - 1 - t0) < TCH) ? (KL - 1 - t0) : TCH;
        // featc rows (tl*128+b): cols [0,512) = e_t, cols [512,1536) = h2
        gather_emb<<<(Tc * KB * 64) / 256, 256, 0, stream>>>(emb_dec, seq, featc, KE + KH, t0);
        // gi = e @ W_ih_d[:, :E]^T  (bias lives in ci) -> bf16
        gemm128<<<dim3(KH3 / 128, (Tc * KB) / 128), 256, 0, stream>>>(
            featc, KE + KH, Wb_ih_d, KE + KH, nullptr, gi, KH3, KE, nullptr, nullptr, 0, 0);
        // Tc recurrent steps (writes h2 into featc cols [512,1536))
        launch_rec(gi, ci, hb, h, featc + KE, Wb_hh_d, b_hh_d, bar, Tc, gen0, stream);
        gen0 += Tc;
        // preds = [e, h2] @ fc_W[:, :E+H]^T + cf  (K=1536, scatter rows t0+tl+1)
        gemm128<<<dim3(KV / 128, (Tc * KB) / 128), 256, 0, stream>>>(
            featc, KE + KH, fc_Wb, KE + 2 * KH, out, nullptr, KV, KE + KH,
            nullptr, cf, 1, t0);
    }
}

// Round 3
// 4724.365 us; speedup vs baseline: 2.4537x; 1.2923x over previous
//
#include <hip/hip_runtime.h>
#include <math.h>

#define KV 2048
#define KE 512
#define KH 1024
#define KB 128
#define KL 256
#define KH3 3072
#define TCH 32
#define NSLOT 33   // hb ring slots: > max steps/dispatch, so no address reuse

typedef __attribute__((ext_vector_type(8))) short s8v;     // 8 bf16 (4 VGPRs)
typedef __attribute__((ext_vector_type(8))) unsigned short u16x8;
typedef __attribute__((ext_vector_type(4))) float f4v;

__device__ __forceinline__ unsigned short f2b(float f) {   // fp32 -> bf16 RNE
    unsigned u = __float_as_uint(f);
    u += 0x7fffu + ((u >> 16) & 1u);
    return (unsigned short)(u >> 16);
}
__device__ __forceinline__ float b2f(unsigned short h) {
    return __uint_as_float(((unsigned)h) << 16);
}

// ---------------------------------------------------------------------------
// Stage ROWS x 64 bf16 tile (row-major, 128B rows) global -> LDS via
// global_load_lds width=16, with XOR-8 chunk swizzle: global chunk c of row r
// stored at LDS slot (c ^ (r&7)). Wave-load = 8 rows (64 lanes x 16B = 1KB).
// ---------------------------------------------------------------------------
template<int ROWS>
__device__ __forceinline__ void stage_tile(unsigned short* lds,
                                           const unsigned short* g, int ld)
{
    const int tid = threadIdx.x;
    const int wave = tid >> 6, lane = tid & 63;
    constexpr int per_wave = ROWS / 32;
    #pragma unroll
    for (int i = 0; i < per_wave; ++i) {
        const int r0 = (wave * per_wave + i) * 8;
        const int r  = r0 + (lane >> 3);
        const int cg = (lane & 7) ^ (r & 7);
        const unsigned short* gp = g + (size_t)r * ld + cg * 8;
        __builtin_amdgcn_global_load_lds(
            (const __attribute__((address_space(1))) unsigned int*)(const void*)gp,
            (__attribute__((address_space(3))) unsigned int*)(void*)(lds + r0 * 64),
            16, 0, 0);
    }
}

// ---------------------------------------------------------------------------
// C(M,N) = A(M,K) @ B(N,K)^T [bf16 in, fp32 acc]. BM=128 BN=128 BK=64,
// 4 waves 2x2, each wave 64x64 = 4x4 MFMA frags. Optional bias[n],
// addrow[row&127][n], scatter (out[(b*L+t0+tl+1)*V + n]), bf16 or f32 store.
// ---------------------------------------------------------------------------
__global__ __launch_bounds__(256)
void gemm128(const unsigned short* __restrict__ A, int lda,
             const unsigned short* __restrict__ Bm, int ldb,
             float* __restrict__ OutF, unsigned short* __restrict__ OutH,
             int N, int K,
             const float* __restrict__ bias,
             const float* __restrict__ addrow,
             int scatter, int t0)
{
    __shared__ unsigned short As[128 * 64];
    __shared__ unsigned short Bs[128 * 64];
    const int tid = threadIdx.x;
    const int wave = tid >> 6, lane = tid & 63;
    const int wm = wave >> 1, wn = wave & 1;
    const int q = lane >> 4, l15 = lane & 15, l7 = lane & 7;
    const int m0 = blockIdx.y * 128, n0 = blockIdx.x * 128;
    f4v acc[4][4] = {};
    for (int kb = 0; kb < K; kb += 64) {
        stage_tile<128>(As, A + (size_t)m0 * lda + kb, lda);
        stage_tile<128>(Bs, Bm + (size_t)n0 * ldb + kb, ldb);
        __syncthreads();
        #pragma unroll
        for (int kk = 0; kk < 2; ++kk) {
            const int ch = (kk * 4 + q) ^ l7;
            s8v a[4], b[4];
            #pragma unroll
            for (int i = 0; i < 4; ++i) {
                a[i] = *(const s8v*)(As + (wm * 64 + i * 16 + l15) * 64 + ch * 8);
                b[i] = *(const s8v*)(Bs + (wn * 64 + i * 16 + l15) * 64 + ch * 8);
            }
            #pragma unroll
            for (int i = 0; i < 4; ++i)
                #pragma unroll
                for (int j = 0; j < 4; ++j)
                    acc[i][j] = __builtin_amdgcn_mfma_f32_16x16x32_bf16(
                        a[i], b[j], acc[i][j], 0, 0, 0);
        }
        __syncthreads();
    }
    #pragma unroll
    for (int i = 0; i < 4; ++i) {
        #pragma unroll
        for (int r = 0; r < 4; ++r) {
            const int row = m0 + wm * 64 + i * 16 + q * 4 + r;
            size_t obase;
            if (scatter) {
                const int bidx = row & 127, tl = row >> 7;
                obase = (size_t)(bidx * KL + t0 + tl + 1) * KV;
            } else {
                obase = (size_t)row * N;
            }
            #pragma unroll
            for (int j = 0; j < 4; ++j) {
                const int col = n0 + wn * 64 + j * 16 + l15;
                float v = acc[i][j][r];
                if (bias)   v += bias[col];
                if (addrow) v += addrow[(size_t)(row & 127) * N + col];
                if (OutF) OutF[obase + col] = v;
                else      OutH[obase + col] = f2b(v);
            }
        }
    }
}

// ---------------------------------------------------------------------------
// Persistent fused recurrence: Tc GRU steps in ONE cooperative launch.
// Grid = 256 blocks x 256 thr. Block b: m-group m = b&3 (rows m*32..+32),
// col-group c = b>>2 (H cols c*16..+16; W rows {g*1024+c*16..+16}).
//
// hb state lives in a 33-slot RING (slot touched at most once per dispatch):
//  - producers store with sc0 sc1 (write-through to LLC; no L2 copy exists)
//  - consumers read with NORMAL cached loads (first touch -> LLC -> L2;
//    8x intra-XCD L2 reuse). Safe because no pre-write L2 line can exist
//    (unique addresses in-dispatch; kernel-boundary acquire across dispatches).
// Per-m-group flags: flags[m*64+c] = gen0+tl+1 after block (m,c) stored its
// slot(tl+1) patch. Consumers poll only their 64 producers (1 dword/lane).
// Step tl: [gi preload] [poll gen0+tl if tl>0] [A normal loads slot(tl)]
// [48 MFMA vs LDS W] [Pp partials, sync] [reduce+GRU EW, Hs repack, sync]
// [wave0: 64x dwordx4 sc0sc1 -> slot(tl+1), vmcnt(0), flag store].
// ---------------------------------------------------------------------------
__global__ __launch_bounds__(256)
void rec_fused(const unsigned short* __restrict__ gi,
               const float* __restrict__ ci,
               unsigned short* hbring,           // [NSLOT][128][1024]
               float* __restrict__ h,            // [128][1024]
               unsigned short* __restrict__ h2,  // featc+KE (ld KE+KH) or null
               const unsigned short* __restrict__ Whh,   // bf16 [3072][1024]
               const float* __restrict__ bhh,
               unsigned* bar, int Tc, unsigned gen0, int slot0)
{
    __shared__ unsigned short Ws[3 * 16 * KH];   // 98304 B, XOR-8 swizzled
    __shared__ float Pp[4 * 6 * 4 * 16 * 4];     // 24576 B wave partials
    __shared__ unsigned short Hs[32 * 16];       // 1024 B h repack
    unsigned* flags = bar + 64;                  // 256 entries [m*64+c]
    const int tid  = threadIdx.x;
    const int wave = tid >> 6, lane = tid & 63;
    const int q = lane >> 4, l15 = lane & 15;
    const int mg  = (int)blockIdx.x & 3;
    const int m0  = mg * 32;
    const int hc0 = ((int)blockIdx.x >> 2) * 16;

    // ---- stage W_hh slice (48 rows x 1024 bf16) -> LDS, slot s holds
    //      global chunk s^(row&7)  (16B chunks, 128 per row) ----
    #pragma unroll
    for (int it = 0; it < 24; ++it) {
        const int gidx = it * 256 + tid;
        const int row  = gidx >> 7;            // 0..47 = g*16 + rr
        const int slot = gidx & 127;
        const int csrc = slot ^ (row & 7);
        const int g = row >> 4, rr = row & 15;
        const unsigned short* src =
            Whh + (size_t)(g * KH + hc0 + rr) * KH + csrc * 8;
        __builtin_amdgcn_global_load_lds(
            (const __attribute__((address_space(1))) unsigned int*)(const void*)src,
            (__attribute__((address_space(3))) unsigned int*)(void*)(Ws + row * KH + slot * 8),
            16, 0, 0);
    }

    // ---- per-thread persistent elementwise state ----
    const int col16 = tid & 15;
    const int rowq  = (tid >> 4) & 15;
    const int qq = rowq >> 2, r4 = rowq & 3;
    const int col = hc0 + col16;
    float bh[3], civ[2][3], hv[2];
    #pragma unroll
    for (int g = 0; g < 3; ++g) bh[g] = bhh[g * KH + col];
    #pragma unroll
    for (int i = 0; i < 2; ++i) {
        const int row = m0 + i * 16 + rowq;
        hv[i] = h[(size_t)row * KH + col];
        #pragma unroll
        for (int g = 0; g < 3; ++g)
            civ[i][g] = ci ? ci[(size_t)row * KH3 + g * KH + col] : 0.0f;
    }
    __syncthreads();   // Ws staged (barrier drains vmcnt)

    const unsigned* fp = flags + mg * 64 + lane;   // this m-group's 64 flags

    for (int tl = 0; tl < Tc; ++tl) {
        int sl = slot0 + tl;       if (sl >= NSLOT) sl -= NSLOT;
        int slw = sl + 1;          if (slw >= NSLOT) slw -= NSLOT;
        const unsigned short* hin  = hbring + (size_t)sl  * KB * KH;
        unsigned short*       hout = hbring + (size_t)slw * KB * KH;

        // gi preload (independent of recurrence) — hides under the poll
        float gir[2][3];
        #pragma unroll
        for (int i = 0; i < 2; ++i) {
            const size_t gib = ((size_t)tl * KB + m0 + i * 16 + rowq) * KH3 + col;
            gir[i][0] = b2f(gi[gib]);
            gir[i][1] = b2f(gi[gib + KH]);
            gir[i][2] = b2f(gi[gib + 2 * KH]);
        }

        // wait for this m-group's 64 producers of slot(tl)
        if (tl > 0) {
            const unsigned tgt = gen0 + (unsigned)tl;
            while (true) {
                unsigned v;
                asm volatile("global_load_dword %0, %1, off sc0 sc1\n\t"
                             "s_waitcnt vmcnt(0)"
                             : "=v"(v) : "v"(fp) : "memory");
                if (!__any((int)(v < tgt))) break;
                __builtin_amdgcn_s_sleep(1);
            }
        }

        // A fragments: NORMAL cached loads (L2-served; addresses unique/step)
        s8v a[2][8];
        #pragma unroll
        for (int i = 0; i < 2; ++i)
            #pragma unroll
            for (int kk = 0; kk < 8; ++kk)
                a[i][kk] = *(const s8v*)(hin +
                    (size_t)(m0 + i * 16 + l15) * KH + wave * 256 + kk * 32 + q * 8);

        f4v acc[2][3] = {};
        #pragma unroll
        for (int kk = 0; kk < 8; ++kk) {
            const int soff = ((wave * 32 + kk * 4 + q) ^ (l15 & 7)) * 8;
            #pragma unroll
            for (int g = 0; g < 3; ++g) {
                const s8v bf = *(const s8v*)(Ws + (g * 16 + l15) * KH + soff);
                acc[0][g] = __builtin_amdgcn_mfma_f32_16x16x32_bf16(
                    a[0][kk], bf, acc[0][g], 0, 0, 0);
                acc[1][g] = __builtin_amdgcn_mfma_f32_16x16x32_bf16(
                    a[1][kk], bf, acc[1][g], 0, 0, 0);
            }
        }
        // wave partials -> LDS (D layout: reg r = row q*4+r, col l15)
        #pragma unroll
        for (int i = 0; i < 2; ++i)
            #pragma unroll
            for (int g = 0; g < 3; ++g)
                *(f4v*)(Pp + (((wave * 6 + i * 3 + g) * 4 + q) * 16 + l15) * 4)
                    = acc[i][g];
        __syncthreads();
        // reduce 4 waves + fused GRU elementwise -> Hs repack (+h2 lazy)
        #pragma unroll
        for (int i = 0; i < 2; ++i) {
            float gs0 = 0.f, gs1 = 0.f, gs2 = 0.f;
            #pragma unroll
            for (int w = 0; w < 4; ++w) {
                const float* p = Pp + ((w * 6 + i * 3) * 4 + qq) * 64
                               + col16 * 4 + r4;
                gs0 += p[0]; gs1 += p[256]; gs2 += p[512];
            }
            const float rg = 1.0f / (1.0f + __expf(-(gir[i][0] + civ[i][0] + gs0 + bh[0])));
            const float zg = 1.0f / (1.0f + __expf(-(gir[i][1] + civ[i][1] + gs1 + bh[1])));
            const float ng = tanhf(gir[i][2] + civ[i][2] + rg * (gs2 + bh[2]));
            hv[i] = (1.0f - zg) * ng + zg * hv[i];
            const unsigned short hb16 = f2b(hv[i]);
            const int li = i * 16 + rowq;
            Hs[li * 16 + col16] = hb16;
            if (h2) h2[((size_t)tl * KB + m0 + li) * (KE + KH) + col] = hb16;
        }
        __syncthreads();   // Hs complete
        // wave 0: 64 coalesced device-scope stores, drain, raise flag
        if (wave == 0) {
            const int row = lane >> 1, half = lane & 1;
            const u16x8 hval = *(const u16x8*)(Hs + row * 16 + half * 8);
            const unsigned short* sp =
                hout + (size_t)(m0 + row) * KH + hc0 + half * 8;
            asm volatile("global_store_dwordx4 %0, %1, off sc0 sc1"
                         :: "v"(sp), "v"(hval) : "memory");
            asm volatile("s_waitcnt vmcnt(0)" ::: "memory");
            if (lane == 0) {
                const unsigned tgt = gen0 + (unsigned)tl + 1u;
                const unsigned* fpw = flags + mg * 64 + ((int)blockIdx.x >> 2);
                asm volatile("global_store_dword %0, %1, off sc0 sc1"
                             :: "v"(fpw), "v"(tgt) : "memory");
            }
        }
    }
    // write back f32 h patch (context for ctx copy / next chunk)
    #pragma unroll
    for (int i = 0; i < 2; ++i)
        h[(size_t)(m0 + i * 16 + rowq) * KH + col] = hv[i];
}

static void launch_rec(const unsigned short* gi, const float* ci,
                       unsigned short* hbring, float* h, unsigned short* h2,
                       const unsigned short* Whh, const float* bhh,
                       unsigned* bar, int Tc, unsigned gen0, int slot0,
                       hipStream_t stream)
{
    void* args[11] = { (void*)&gi, (void*)&ci, (void*)&hbring, (void*)&h,
                       (void*)&h2, (void*)&Whh, (void*)&bhh, (void*)&bar,
                       (void*)&Tc, (void*)&gen0, (void*)&slot0 };
    hipLaunchCooperativeKernel((const void*)rec_fused, dim3(256), dim3(256),
                               args, 0, stream);
}

// X[tl*128+b, 0:512] = bf16(emb[seq[b, t0+tl], :]), row stride ldx
__global__ __launch_bounds__(256)
void gather_emb(const float* __restrict__ emb, const int* __restrict__ seq,
                unsigned short* __restrict__ X, int ldx, int t0)
{
    const int idx = blockIdx.x * 256 + threadIdx.x;   // Tc*B*64
    const int e8 = idx & 63;
    const int rr = idx >> 6;
    const int b = rr & 127, tl = rr >> 7;
    const int tok = seq[b * KL + t0 + tl];
    const float4* src = (const float4*)(emb + (size_t)tok * KE + e8 * 8);
    const float4 v0 = src[0], v1 = src[1];
    u16x8 o;
    o[0] = f2b(v0.x); o[1] = f2b(v0.y); o[2] = f2b(v0.z); o[3] = f2b(v0.w);
    o[4] = f2b(v1.x); o[5] = f2b(v1.y); o[6] = f2b(v1.z); o[7] = f2b(v1.w);
    *(u16x8*)(X + (size_t)rr * ldx + e8 * 8) = o;
}

__global__ __launch_bounds__(256)
void f32tobf16(const float* __restrict__ src, unsigned short* __restrict__ dst, int n)
{
    const int i = (blockIdx.x * 256 + threadIdx.x) * 4;
    if (i < n) {
        const float4 v = *(const float4*)(src + i);
        dst[i] = f2b(v.x); dst[i + 1] = f2b(v.y);
        dst[i + 2] = f2b(v.z); dst[i + 3] = f2b(v.w);
    }
}

__global__ __launch_bounds__(256)
void zero_f32(float* __restrict__ p, int n)
{
    const int i = blockIdx.x * 256 + threadIdx.x;
    if (i < n) p[i] = 0.0f;
}

__global__ __launch_bounds__(256)
void zero_u16(unsigned short* __restrict__ p, int n)
{
    const int i = blockIdx.x * 256 + threadIdx.x;
    if (i < n) p[i] = 0;
}

__global__ __launch_bounds__(256)
void copy_f32(float* __restrict__ dst, const float* __restrict__ src, int n)
{
    const int i = blockIdx.x * 256 + threadIdx.x;
    if (i < n) dst[i] = src[i];
}

__global__ __launch_bounds__(256)
void zero_row0(float* __restrict__ out)
{
    const int idx = blockIdx.x * 256 + threadIdx.x;   // B*V
    const int b = idx >> 11, v = idx & (KV - 1);
    out[(size_t)b * KL * KV + v] = 0.0f;
}

extern "C" void kernel_launch(void* const* d_in, const int* in_sizes, int n_in,
                              void* d_out, int out_size, void* d_ws, size_t ws_size,
                              hipStream_t stream)
{
    (void)in_sizes; (void)n_in; (void)out_size; (void)ws_size;
    const int*   seq     = (const int*)  d_in[0];
    const float* emb_enc = (const float*)d_in[2];
    const float* W_ih_e  = (const float*)d_in[3];
    const float* W_hh_e  = (const float*)d_in[4];
    const float* b_ih_e  = (const float*)d_in[5];
    const float* b_hh_e  = (const float*)d_in[6];
    const float* emb_dec = (const float*)d_in[7];
    const float* W_ih_d  = (const float*)d_in[8];   // (3H, E+H)
    const float* W_hh_d  = (const float*)d_in[9];
    const float* b_ih_d  = (const float*)d_in[10];
    const float* b_hh_d  = (const float*)d_in[11];
    const float* fc_W    = (const float*)d_in[12];  // (V, E+2H)
    const float* fc_b    = (const float*)d_in[13];
    float* out = (float*)d_out;

    // ---- workspace layout (~89.6 MB) ----
    char* w = (char*)d_ws;
    unsigned*       bar     = (unsigned*)w;                  w += 2048;
    unsigned short* Wb_ih_e = (unsigned short*)w;            w += (size_t)KH3 * KE * 2;
    unsigned short* Wb_hh_e = (unsigned short*)w;            w += (size_t)KH3 * KH * 2;
    unsigned short* Wb_ih_d = (unsigned short*)w;            w += (size_t)KH3 * (KE + KH) * 2;
    unsigned short* Wb_hh_d = (unsigned short*)w;            w += (size_t)KH3 * KH * 2;
    unsigned short* fc_Wb   = (unsigned short*)w;            w += (size_t)KV * (KE + 2 * KH) * 2;
    float*          h       = (float*)w;                     w += (size_t)KB * KH * 4;
    unsigned short* hbring  = (unsigned short*)w;            w += (size_t)NSLOT * KB * KH * 2;
    float*          ci      = (float*)w;                     w += (size_t)KB * KH3 * 4;
    float*          cf      = (float*)w;                     w += (size_t)KB * KV * 4;
    unsigned short* gi      = (unsigned short*)w;            w += (size_t)TCH * KB * KH3 * 2;
    unsigned short* featc   = (unsigned short*)w;            w += (size_t)TCH * KB * (KE + KH) * 2;

    // ---- weight conversion to bf16 ----
    f32tobf16<<<(KH3 * KE) / 1024, 256, 0, stream>>>(W_ih_e, Wb_ih_e, KH3 * KE);
    f32tobf16<<<(KH3 * KH) / 1024, 256, 0, stream>>>(W_hh_e, Wb_hh_e, KH3 * KH);
    f32tobf16<<<(KH3 * (KE + KH)) / 1024, 256, 0, stream>>>(W_ih_d, Wb_ih_d, KH3 * (KE + KH));
    f32tobf16<<<(KH3 * KH) / 1024, 256, 0, stream>>>(W_hh_d, Wb_hh_d, KH3 * KH);
    f32tobf16<<<(KV * (KE + 2 * KH)) / 1024, 256, 0, stream>>>(fc_W, fc_Wb, KV * (KE + 2 * KH));

    zero_f32<<<2, 256, 0, stream>>>((float*)bar, 512);       // flags = 0
    zero_f32<<<(KB * KH) / 256, 256, 0, stream>>>(h, KB * KH);
    zero_u16<<<(KB * KH) / 256, 256, 0, stream>>>(hbring, KB * KH);  // slot 0

    unsigned gen0 = 0;
    int slot = 0;

    // ---------------- Encoder ----------------
    for (int t0 = 0; t0 < KL; t0 += TCH) {
        unsigned short* Xc = featc;   // bf16 embeddings staging, ld=512
        gather_emb<<<(TCH * KB * 64) / 256, 256, 0, stream>>>(emb_enc, seq, Xc, KE, t0);
        // gi = Xc @ W_ih_e^T + b_ih_e   (M=4096, N=3072, K=512) -> bf16
        gemm128<<<dim3(KH3 / 128, (TCH * KB) / 128), 256, 0, stream>>>(
            Xc, KE, Wb_ih_e, KE, nullptr, gi, KH3, KE, b_ih_e, nullptr, 0, 0);
        // 32 recurrent steps in one cooperative launch
        launch_rec(gi, nullptr, hbring, h, nullptr, Wb_hh_e, b_hh_e, bar,
                   TCH, gen0, slot, stream);
        gen0 += TCH;
        slot = (slot + TCH) % NSLOT;
    }

    const unsigned short* ctxb = hbring + (size_t)slot * KB * KH;

    // context -> d_out; mu = log_var = 0; outputs[:,0,:] = 0
    float* ctx_out = out + (size_t)KB * KL * KV;
    copy_f32<<<(KB * KH) / 256, 256, 0, stream>>>(ctx_out, h, KB * KH);
    zero_f32<<<(2 * KB * KH) / 256, 256, 0, stream>>>(ctx_out + KB * KH, 2 * KB * KH);
    zero_row0<<<(KB * KV) / 256, 256, 0, stream>>>(out);

    // ci = context @ W_ih_d[:, E:]^T + b_ih_d   (M=128, N=3072, K=1024)
    gemm128<<<dim3(KH3 / 128, 1), 256, 0, stream>>>(
        ctxb, KH, Wb_ih_d + KE, KE + KH, ci, nullptr, KH3, KH, b_ih_d, nullptr, 0, 0);
    // cf = context @ fc_W[:, E+H:]^T + fc_b     (M=128, N=2048, K=1024)
    gemm128<<<dim3(KV / 128, 1), 256, 0, stream>>>(
        ctxb, KH, fc_Wb + (KE + KH), KE + 2 * KH, cf, nullptr, KV, KH, fc_b, nullptr, 0, 0);

    // ---------------- Decoder ---------------- (h/ring[slot] = context)
    for (int t0 = 0; t0 < KL - 1; t0 += TCH) {
        const int Tc = ((KL - 1 - t0) < TCH) ? (KL - 1 - t0) : TCH;
        // featc rows (tl*128+b): cols [0,512) = e_t, cols [512,1536) = h2
        gather_emb<<<(Tc * KB * 64) / 256, 256, 0, stream>>>(emb_dec, seq, featc, KE + KH, t0);
        // gi = e @ W_ih_d[:, :E]^T  (bias lives in ci) -> bf16
        gemm128<<<dim3(KH3 / 128, (Tc * KB) / 128), 256, 0, stream>>>(
            featc, KE + KH, Wb_ih_d, KE + KH, nullptr, gi, KH3, KE, nullptr, nullptr, 0, 0);
        // Tc recurrent steps (writes h2 into featc cols [512,1536))
        launch_rec(gi, ci, hbring, h, featc + KE, Wb_hh_d, b_hh_d, bar,
                   Tc, gen0, slot, stream);
        gen0 += Tc;
        slot = (slot + Tc) % NSLOT;
        // preds = [e, h2] @ fc_W[:, :E+H]^T + cf  (K=1536, scatter rows t0+tl+1)
        gemm128<<<dim3(KV / 128, (Tc * KB) / 128), 256, 0, stream>>>(
            featc, KE + KH, fc_Wb, KE + 2 * KH, out, nullptr, KV, KE + KH,
            nullptr, cf, 1, t0);
    }
}

// Round 4
// 4268.481 us; speedup vs baseline: 2.7157x; 1.1068x over previous
//
#include <hip/hip_runtime.h>
#include <math.h>

#define KV 2048
#define KE 512
#define KH 1024
#define KB 128
#define KL 256
#define KH3 3072
#define TCH 32
#define NSLOT 33   // hb ring slots: > max steps/dispatch, so no address reuse

typedef __attribute__((ext_vector_type(8))) short s8v;     // 8 bf16 (4 VGPRs)
typedef __attribute__((ext_vector_type(8))) unsigned short u16x8;
typedef __attribute__((ext_vector_type(4))) float f4v;

__device__ __forceinline__ unsigned short f2b(float f) {   // fp32 -> bf16 RNE
    unsigned u = __float_as_uint(f);
    u += 0x7fffu + ((u >> 16) & 1u);
    return (unsigned short)(u >> 16);
}
__device__ __forceinline__ float b2f(unsigned short h) {
    return __uint_as_float(((unsigned)h) << 16);
}

// ---------------------------------------------------------------------------
// Stage ROWS x 64 bf16 tile (row-major, 128B rows) global -> LDS via
// global_load_lds width=16, with XOR-8 chunk swizzle: global chunk c of row r
// stored at LDS slot (c ^ (r&7)). Wave-load = 8 rows (64 lanes x 16B = 1KB).
// ---------------------------------------------------------------------------
template<int ROWS>
__device__ __forceinline__ void stage_tile(unsigned short* lds,
                                           const unsigned short* g, int ld)
{
    const int tid = threadIdx.x;
    const int wave = tid >> 6, lane = tid & 63;
    constexpr int per_wave = ROWS / 32;
    #pragma unroll
    for (int i = 0; i < per_wave; ++i) {
        const int r0 = (wave * per_wave + i) * 8;
        const int r  = r0 + (lane >> 3);
        const int cg = (lane & 7) ^ (r & 7);
        const unsigned short* gp = g + (size_t)r * ld + cg * 8;
        __builtin_amdgcn_global_load_lds(
            (const __attribute__((address_space(1))) unsigned int*)(const void*)gp,
            (__attribute__((address_space(3))) unsigned int*)(void*)(lds + r0 * 64),
            16, 0, 0);
    }
}

// ---------------------------------------------------------------------------
// C(M,N) = A(M,K) @ B(N,K)^T [bf16 in, fp32 acc]. BM=128 BN=128 BK=64,
// 4 waves 2x2, each wave 64x64 = 4x4 MFMA frags. Optional bias[n],
// addrow[row&127][n], scatter (out[(b*L+t0+tl+1)*V + n]), bf16 or f32 store.
// ---------------------------------------------------------------------------
__global__ __launch_bounds__(256)
void gemm128(const unsigned short* __restrict__ A, int lda,
             const unsigned short* __restrict__ Bm, int ldb,
             float* __restrict__ OutF, unsigned short* __restrict__ OutH,
             int N, int K,
             const float* __restrict__ bias,
             const float* __restrict__ addrow,
             int scatter, int t0)
{
    __shared__ unsigned short As[128 * 64];
    __shared__ unsigned short Bs[128 * 64];
    const int tid = threadIdx.x;
    const int wave = tid >> 6, lane = tid & 63;
    const int wm = wave >> 1, wn = wave & 1;
    const int q = lane >> 4, l15 = lane & 15, l7 = lane & 7;
    const int m0 = blockIdx.y * 128, n0 = blockIdx.x * 128;
    f4v acc[4][4] = {};
    for (int kb = 0; kb < K; kb += 64) {
        stage_tile<128>(As, A + (size_t)m0 * lda + kb, lda);
        stage_tile<128>(Bs, Bm + (size_t)n0 * ldb + kb, ldb);
        __syncthreads();
        #pragma unroll
        for (int kk = 0; kk < 2; ++kk) {
            const int ch = (kk * 4 + q) ^ l7;
            s8v a[4], b[4];
            #pragma unroll
            for (int i = 0; i < 4; ++i) {
                a[i] = *(const s8v*)(As + (wm * 64 + i * 16 + l15) * 64 + ch * 8);
                b[i] = *(const s8v*)(Bs + (wn * 64 + i * 16 + l15) * 64 + ch * 8);
            }
            #pragma unroll
            for (int i = 0; i < 4; ++i)
                #pragma unroll
                for (int j = 0; j < 4; ++j)
                    acc[i][j] = __builtin_amdgcn_mfma_f32_16x16x32_bf16(
                        a[i], b[j], acc[i][j], 0, 0, 0);
        }
        __syncthreads();
    }
    #pragma unroll
    for (int i = 0; i < 4; ++i) {
        #pragma unroll
        for (int r = 0; r < 4; ++r) {
            const int row = m0 + wm * 64 + i * 16 + q * 4 + r;
            size_t obase;
            if (scatter) {
                const int bidx = row & 127, tl = row >> 7;
                obase = (size_t)(bidx * KL + t0 + tl + 1) * KV;
            } else {
                obase = (size_t)row * N;
            }
            #pragma unroll
            for (int j = 0; j < 4; ++j) {
                const int col = n0 + wn * 64 + j * 16 + l15;
                float v = acc[i][j][r];
                if (bias)   v += bias[col];
                if (addrow) v += addrow[(size_t)(row & 127) * N + col];
                if (OutF) OutF[obase + col] = v;
                else      OutH[obase + col] = f2b(v);
            }
        }
    }
}

// ---------------------------------------------------------------------------
// Persistent fused recurrence: Tc GRU steps in ONE cooperative launch.
// Grid = 256 blocks x 256 thr. Block b: m-group mg = b&3 (rows mg*32..+32),
// col-group c = b>>2 (H cols c*16..+16; W rows {g*1024+c*16..+16}).
//
// hb state lives in a 33-slot RING (each slot address touched at most once
// per dispatch): producers store sc0 sc1 (write-through to coherence point,
// no L2 copy), consumers use NORMAL cached loads (LLC -> L2, intra-XCD
// reuse). Cross-dispatch reuse is covered by kernel-boundary acquire.
//
// Sync: ONE arrival counter per m-group (256B apart). Producer block:
// dword sc0sc1 stores (1 row x 2 cols per thread) -> vmcnt(0) -> barrier ->
// tid0 relaxed agent-scope atomic_add(cnt,1). Monotone invariant:
// cnt[mg] == 64 * (global steps completed). Consumer: all 64 lanes poll the
// SAME address (1 line request per wave per round), uniform exit when
// cnt >= 64*(gen0+tl). No flag arrays, no gathered polls, no L2 flushes.
// ---------------------------------------------------------------------------
__global__ __launch_bounds__(256)
void rec_fused(const unsigned short* __restrict__ gi,
               const float* __restrict__ ci,
               unsigned short* hbring,           // [NSLOT][128][1024]
               float* __restrict__ h,            // [128][1024]
               unsigned short* __restrict__ h2,  // featc+KE (ld KE+KH) or null
               const unsigned short* __restrict__ Whh,   // bf16 [3072][1024]
               const float* __restrict__ bhh,
               unsigned* bar, int Tc, unsigned gen0, int slot0)
{
    __shared__ unsigned short Ws[3 * 16 * KH];   // 98304 B, XOR-8 swizzled
    __shared__ float Pp[4 * 6 * 4 * 16 * 4];     // 24576 B wave partials
    const int tid  = threadIdx.x;
    const int wave = tid >> 6, lane = tid & 63;
    const int q = lane >> 4, l15 = lane & 15;
    const int mg  = (int)blockIdx.x & 3;
    const int m0  = mg * 32;
    const int hc0 = ((int)blockIdx.x >> 2) * 16;
    unsigned* cnt = bar + mg * 64;               // 4 counters, 256B apart

    // ---- stage W_hh slice (48 rows x 1024 bf16) -> LDS, slot s holds
    //      global chunk s^(row&7)  (16B chunks, 128 per row) ----
    #pragma unroll
    for (int it = 0; it < 24; ++it) {
        const int gidx = it * 256 + tid;
        const int row  = gidx >> 7;            // 0..47 = g*16 + rr
        const int slot = gidx & 127;
        const int csrc = slot ^ (row & 7);
        const int g = row >> 4, rr = row & 15;
        const unsigned short* src =
            Whh + (size_t)(g * KH + hc0 + rr) * KH + csrc * 8;
        __builtin_amdgcn_global_load_lds(
            (const __attribute__((address_space(1))) unsigned int*)(const void*)src,
            (__attribute__((address_space(3))) unsigned int*)(void*)(Ws + row * KH + slot * 8),
            16, 0, 0);
    }

    // ---- per-thread persistent EW state: 1 row x 2 adjacent cols ----
    const int erow = tid >> 3;                 // 0..31 local row
    const int cp   = (tid & 7) * 2;            // local col pair
    const int i_   = erow >> 4;                // 16-row half (Pp index)
    const int qq   = (erow >> 2) & 3;
    const int r4   = erow & 3;
    const int grow = m0 + erow;                // global row
    const int gcol = hc0 + cp;                 // global col (even)
    float bh0[3], bh1[3], civ0[3], civ1[3];
    float hv0, hv1;
    #pragma unroll
    for (int g = 0; g < 3; ++g) {
        bh0[g] = bhh[g * KH + gcol];
        bh1[g] = bhh[g * KH + gcol + 1];
        if (ci) {
            civ0[g] = ci[(size_t)grow * KH3 + g * KH + gcol];
            civ1[g] = ci[(size_t)grow * KH3 + g * KH + gcol + 1];
        } else { civ0[g] = 0.0f; civ1[g] = 0.0f; }
    }
    hv0 = h[(size_t)grow * KH + gcol];
    hv1 = h[(size_t)grow * KH + gcol + 1];
    __syncthreads();   // Ws staged (barrier drains vmcnt)

    for (int tl = 0; tl < Tc; ++tl) {
        int sl = slot0 + tl;       if (sl >= NSLOT) sl -= NSLOT;
        int slw = sl + 1;          if (slw >= NSLOT) slw -= NSLOT;
        const unsigned short* hin  = hbring + (size_t)sl  * KB * KH;
        unsigned short*       hout = hbring + (size_t)slw * KB * KH;

        // gi preload (3 dwords = 6 bf16) — latency hides under the poll
        unsigned giw[3];
        #pragma unroll
        for (int g = 0; g < 3; ++g)
            giw[g] = *(const unsigned*)(gi +
                ((size_t)tl * KB + grow) * KH3 + g * KH + gcol);

        // wait for this m-group's 64 producers of slot(tl): uniform poll of
        // ONE counter (all lanes same address -> 1 line request per wave)
        if (tl > 0) {
            const unsigned tgt = 64u * (gen0 + (unsigned)tl);
            while (true) {
                unsigned v;
                asm volatile("global_load_dword %0, %1, off sc0 sc1\n\t"
                             "s_waitcnt vmcnt(0)"
                             : "=v"(v) : "v"(cnt) : "memory");
                if (v >= tgt) break;
                __builtin_amdgcn_s_sleep(1);
            }
        }

        // A fragments: NORMAL cached loads (L2-served; addresses unique/step)
        s8v a[2][8];
        #pragma unroll
        for (int i = 0; i < 2; ++i)
            #pragma unroll
            for (int kk = 0; kk < 8; ++kk)
                a[i][kk] = *(const s8v*)(hin +
                    (size_t)(m0 + i * 16 + l15) * KH + wave * 256 + kk * 32 + q * 8);

        f4v acc[2][3] = {};
        #pragma unroll
        for (int kk = 0; kk < 8; ++kk) {
            const int soff = ((wave * 32 + kk * 4 + q) ^ (l15 & 7)) * 8;
            #pragma unroll
            for (int g = 0; g < 3; ++g) {
                const s8v bf = *(const s8v*)(Ws + (g * 16 + l15) * KH + soff);
                acc[0][g] = __builtin_amdgcn_mfma_f32_16x16x32_bf16(
                    a[0][kk], bf, acc[0][g], 0, 0, 0);
                acc[1][g] = __builtin_amdgcn_mfma_f32_16x16x32_bf16(
                    a[1][kk], bf, acc[1][g], 0, 0, 0);
            }
        }
        // wave partials -> LDS (D layout: reg r = row q*4+r, col l15)
        #pragma unroll
        for (int i = 0; i < 2; ++i)
            #pragma unroll
            for (int g = 0; g < 3; ++g)
                *(f4v*)(Pp + (((wave * 6 + i * 3 + g) * 4 + q) * 16 + l15) * 4)
                    = acc[i][g];
        __syncthreads();

        // reduce 4 waves + fused GRU EW for (erow, cp..cp+1)
        float gs0[3], gs1[3];
        #pragma unroll
        for (int g = 0; g < 3; ++g) { gs0[g] = 0.f; gs1[g] = 0.f; }
        #pragma unroll
        for (int w = 0; w < 4; ++w)
            #pragma unroll
            for (int g = 0; g < 3; ++g) {
                const float* p = Pp + ((w * 6 + i_ * 3 + g) * 4 + qq) * 64 + r4;
                gs0[g] += p[cp * 4];
                gs1[g] += p[cp * 4 + 4];
            }
        const float rg0 = 1.0f / (1.0f + __expf(-(b2f((unsigned short)(giw[0] & 0xffff)) + civ0[0] + gs0[0] + bh0[0])));
        const float zg0 = 1.0f / (1.0f + __expf(-(b2f((unsigned short)(giw[1] & 0xffff)) + civ0[1] + gs0[1] + bh0[1])));
        const float ng0 = tanhf(b2f((unsigned short)(giw[2] & 0xffff)) + civ0[2] + rg0 * (gs0[2] + bh0[2]));
        hv0 = (1.0f - zg0) * ng0 + zg0 * hv0;
        const float rg1 = 1.0f / (1.0f + __expf(-(b2f((unsigned short)(giw[0] >> 16)) + civ1[0] + gs1[0] + bh1[0])));
        const float zg1 = 1.0f / (1.0f + __expf(-(b2f((unsigned short)(giw[1] >> 16)) + civ1[1] + gs1[1] + bh1[1])));
        const float ng1 = tanhf(b2f((unsigned short)(giw[2] >> 16)) + civ1[2] + rg1 * (gs1[2] + bh1[2]));
        hv1 = (1.0f - zg1) * ng1 + zg1 * hv1;

        const unsigned hpack = (unsigned)f2b(hv0) | ((unsigned)f2b(hv1) << 16);
        // direct device-scope dword store of the (row, colpair) result
        const unsigned short* sp = hout + (size_t)grow * KH + gcol;
        asm volatile("global_store_dword %0, %1, off sc0 sc1"
                     :: "v"(sp), "v"(hpack) : "memory");
        if (h2)
            *(unsigned*)(h2 + ((size_t)tl * KB + grow) * (KE + KH) + gcol) = hpack;

        asm volatile("s_waitcnt vmcnt(0)" ::: "memory");   // this wave's stores
        __syncthreads();                                   // whole block done
        if (tid == 0)
            __hip_atomic_fetch_add(cnt, 1u, __ATOMIC_RELAXED,
                                   __HIP_MEMORY_SCOPE_AGENT);
    }
    // write back f32 h patch (context for ctx copy / next chunk)
    *(float2*)(h + (size_t)grow * KH + gcol) = make_float2(hv0, hv1);
}

static void launch_rec(const unsigned short* gi, const float* ci,
                       unsigned short* hbring, float* h, unsigned short* h2,
                       const unsigned short* Whh, const float* bhh,
                       unsigned* bar, int Tc, unsigned gen0, int slot0,
                       hipStream_t stream)
{
    void* args[11] = { (void*)&gi, (void*)&ci, (void*)&hbring, (void*)&h,
                       (void*)&h2, (void*)&Whh, (void*)&bhh, (void*)&bar,
                       (void*)&Tc, (void*)&gen0, (void*)&slot0 };
    hipLaunchCooperativeKernel((const void*)rec_fused, dim3(256), dim3(256),
                               args, 0, stream);
}

// X[tl*128+b, 0:512] = bf16(emb[seq[b, t0+tl], :]), row stride ldx
__global__ __launch_bounds__(256)
void gather_emb(const float* __restrict__ emb, const int* __restrict__ seq,
                unsigned short* __restrict__ X, int ldx, int t0)
{
    const int idx = blockIdx.x * 256 + threadIdx.x;   // Tc*B*64
    const int e8 = idx & 63;
    const int rr = idx >> 6;
    const int b = rr & 127, tl = rr >> 7;
    const int tok = seq[b * KL + t0 + tl];
    const float4* src = (const float4*)(emb + (size_t)tok * KE + e8 * 8);
    const float4 v0 = src[0], v1 = src[1];
    u16x8 o;
    o[0] = f2b(v0.x); o[1] = f2b(v0.y); o[2] = f2b(v0.z); o[3] = f2b(v0.w);
    o[4] = f2b(v1.x); o[5] = f2b(v1.y); o[6] = f2b(v1.z); o[7] = f2b(v1.w);
    *(u16x8*)(X + (size_t)rr * ldx + e8 * 8) = o;
}

__global__ __launch_bounds__(256)
void f32tobf16(const float* __restrict__ src, unsigned short* __restrict__ dst, int n)
{
    const int i = (blockIdx.x * 256 + threadIdx.x) * 4;
    if (i < n) {
        const float4 v = *(const float4*)(src + i);
        dst[i] = f2b(v.x); dst[i + 1] = f2b(v.y);
        dst[i + 2] = f2b(v.z); dst[i + 3] = f2b(v.w);
    }
}

__global__ __launch_bounds__(256)
void zero_f32(float* __restrict__ p, int n)
{
    const int i = blockIdx.x * 256 + threadIdx.x;
    if (i < n) p[i] = 0.0f;
}

__global__ __launch_bounds__(256)
void zero_u16(unsigned short* __restrict__ p, int n)
{
    const int i = blockIdx.x * 256 + threadIdx.x;
    if (i < n) p[i] = 0;
}

__global__ __launch_bounds__(256)
void copy_f32(float* __restrict__ dst, const float* __restrict__ src, int n)
{
    const int i = blockIdx.x * 256 + threadIdx.x;
    if (i < n) dst[i] = src[i];
}

__global__ __launch_bounds__(256)
void zero_row0(float* __restrict__ out)
{
    const int idx = blockIdx.x * 256 + threadIdx.x;   // B*V
    const int b = idx >> 11, v = idx & (KV - 1);
    out[(size_t)b * KL * KV + v] = 0.0f;
}

extern "C" void kernel_launch(void* const* d_in, const int* in_sizes, int n_in,
                              void* d_out, int out_size, void* d_ws, size_t ws_size,
                              hipStream_t stream)
{
    (void)in_sizes; (void)n_in; (void)out_size; (void)ws_size;
    const int*   seq     = (const int*)  d_in[0];
    const float* emb_enc = (const float*)d_in[2];
    const float* W_ih_e  = (const float*)d_in[3];
    const float* W_hh_e  = (const float*)d_in[4];
    const float* b_ih_e  = (const float*)d_in[5];
    const float* b_hh_e  = (const float*)d_in[6];
    const float* emb_dec = (const float*)d_in[7];
    const float* W_ih_d  = (const float*)d_in[8];   // (3H, E+H)
    const float* W_hh_d  = (const float*)d_in[9];
    const float* b_ih_d  = (const float*)d_in[10];
    const float* b_hh_d  = (const float*)d_in[11];
    const float* fc_W    = (const float*)d_in[12];  // (V, E+2H)
    const float* fc_b    = (const float*)d_in[13];
    float* out = (float*)d_out;

    // ---- workspace layout (~89.6 MB) ----
    char* w = (char*)d_ws;
    unsigned*       bar     = (unsigned*)w;                  w += 2048;
    unsigned short* Wb_ih_e = (unsigned short*)w;            w += (size_t)KH3 * KE * 2;
    unsigned short* Wb_hh_e = (unsigned short*)w;            w += (size_t)KH3 * KH * 2;
    unsigned short* Wb_ih_d = (unsigned short*)w;            w += (size_t)KH3 * (KE + KH) * 2;
    unsigned short* Wb_hh_d = (unsigned short*)w;            w += (size_t)KH3 * KH * 2;
    unsigned short* fc_Wb   = (unsigned short*)w;            w += (size_t)KV * (KE + 2 * KH) * 2;
    float*          h       = (float*)w;                     w += (size_t)KB * KH * 4;
    unsigned short* hbring  = (unsigned short*)w;            w += (size_t)NSLOT * KB * KH * 2;
    float*          ci      = (float*)w;                     w += (size_t)KB * KH3 * 4;
    float*          cf      = (float*)w;                     w += (size_t)KB * KV * 4;
    unsigned short* gi      = (unsigned short*)w;            w += (size_t)TCH * KB * KH3 * 2;
    unsigned short* featc   = (unsigned short*)w;            w += (size_t)TCH * KB * (KE + KH) * 2;

    // ---- weight conversion to bf16 ----
    f32tobf16<<<(KH3 * KE) / 1024, 256, 0, stream>>>(W_ih_e, Wb_ih_e, KH3 * KE);
    f32tobf16<<<(KH3 * KH) / 1024, 256, 0, stream>>>(W_hh_e, Wb_hh_e, KH3 * KH);
    f32tobf16<<<(KH3 * (KE + KH)) / 1024, 256, 0, stream>>>(W_ih_d, Wb_ih_d, KH3 * (KE + KH));
    f32tobf16<<<(KH3 * KH) / 1024, 256, 0, stream>>>(W_hh_d, Wb_hh_d, KH3 * KH);
    f32tobf16<<<(KV * (KE + 2 * KH)) / 1024, 256, 0, stream>>>(fc_W, fc_Wb, KV * (KE + 2 * KH));

    zero_f32<<<2, 256, 0, stream>>>((float*)bar, 512);       // counters = 0
    zero_f32<<<(KB * KH) / 256, 256, 0, stream>>>(h, KB * KH);
    zero_u16<<<(KB * KH) / 256, 256, 0, stream>>>(hbring, KB * KH);  // slot 0

    unsigned gen0 = 0;
    int slot = 0;

    // ---------------- Encoder ----------------
    for (int t0 = 0; t0 < KL; t0 += TCH) {
        unsigned short* Xc = featc;   // bf16 embeddings staging, ld=512
        gather_emb<<<(TCH * KB * 64) / 256, 256, 0, stream>>>(emb_enc, seq, Xc, KE, t0);
        // gi = Xc @ W_ih_e^T + b_ih_e   (M=4096, N=3072, K=512) -> bf16
        gemm128<<<dim3(KH3 / 128, (TCH * KB) / 128), 256, 0, stream>>>(
            Xc, KE, Wb_ih_e, KE, nullptr, gi, KH3, KE, b_ih_e, nullptr, 0, 0);
        // 32 recurrent steps in one cooperative launch
        launch_rec(gi, nullptr, hbring, h, nullptr, Wb_hh_e, b_hh_e, bar,
                   TCH, gen0, slot, stream);
        gen0 += TCH;
        slot = (slot + TCH) % NSLOT;
    }

    const unsigned short* ctxb = hbring + (size_t)slot * KB * KH;

    // context -> d_out; mu = log_var = 0; outputs[:,0,:] = 0
    float* ctx_out = out + (size_t)KB * KL * KV;
    copy_f32<<<(KB * KH) / 256, 256, 0, stream>>>(ctx_out, h, KB * KH);
    zero_f32<<<(2 * KB * KH) / 256, 256, 0, stream>>>(ctx_out + KB * KH, 2 * KB * KH);
    zero_row0<<<(KB * KV) / 256, 256, 0, stream>>>(out);

    // ci = context @ W_ih_d[:, E:]^T + b_ih_d   (M=128, N=3072, K=1024)
    gemm128<<<dim3(KH3 / 128, 1), 256, 0, stream>>>(
        ctxb, KH, Wb_ih_d + KE, KE + KH, ci, nullptr, KH3, KH, b_ih_d, nullptr, 0, 0);
    // cf = context @ fc_W[:, E+H:]^T + fc_b     (M=128, N=2048, K=1024)
    gemm128<<<dim3(KV / 128, 1), 256, 0, stream>>>(
        ctxb, KH, fc_Wb + (KE + KH), KE + 2 * KH, cf, nullptr, KV, KH, fc_b, nullptr, 0, 0);

    // ---------------- Decoder ---------------- (h/ring[slot] = context)
    for (int t0 = 0; t0 < KL - 1; t0 += TCH) {
        const int Tc = ((KL - 1 - t0) < TCH) ? (KL - 1 - t0) : TCH;
        // featc rows (tl*128+b): cols [0,512) = e_t, cols [512,1536) = h2
        gather_emb<<<(Tc * KB * 64) / 256, 256, 0, stream>>>(emb_dec, seq, featc, KE + KH, t0);
        // gi = e @ W_ih_d[:, :E]^T  (bias lives in ci) -> bf16
        gemm128<<<dim3(KH3 / 128, (Tc * KB) / 128), 256, 0, stream>>>(
            featc, KE + KH, Wb_ih_d, KE + KH, nullptr, gi, KH3, KE, nullptr, nullptr, 0, 0);
        // Tc recurrent steps (writes h2 into featc cols [512,1536))
        launch_rec(gi, ci, hbring, h, featc + KE, Wb_hh_d, b_hh_d, bar,
                   Tc, gen0, slot, stream);
        gen0 += Tc;
        slot = (slot + Tc) % NSLOT;
        // preds = [e, h2] @ fc_W[:, :E+H]^T + cf  (K=1536, scatter rows t0+tl+1)
        gemm128<<<dim3(KV / 128, (Tc * KB) / 128), 256, 0, stream>>>(
            featc, KE + KH, fc_Wb, KE + 2 * KH, out, nullptr, KV, KE + KH,
            nullptr, cf, 1, t0);
    }
}